// Round 14
// baseline (419.233 us; speedup 1.0000x reference)
//
#include <hip/hip_runtime.h>

// GCN 2-layer. Round-13 post-mortem: all our kernels <115us (fills bound).
// Arithmetic: old gemm1 = 2 ds_read_b128 per 4 FMA = 6.4M LDS wave-insts
// ~= 125us LDS-throughput-bound. Fix: 4x4 register blocking (8 b128 per 64
// FMA, 4x fewer), swizzled x tile (aligned + conflict-free), 64KB LDS ->
// 2 blocks/CU. sumdeg fused into scan. Everything else verified earlier.

#define NF 512
#define NH 16
#define NRANGE 32
#define NS2 32
#define RS 3125           // nodes per range = 100000/32
#define EB 1024           // edges per bin block
#define GROWS 256         // gemm rows per block
#define GK 32             // gemm k-chunk

// ---- ws layout (4B units) ----
// dinv @0 (100000) | (spare @100000) | bsum @200000 (1024)
// rowptr @201024 (100001) | bsum2 @301056 (1024)
// bktcnt @302080 (100032, scanned in place)
// partials @402112 (NRANGE*NS2*RS = 3.2M)
// csr int2 @3602112 (2E) | bin int2 @10002112 (2E, dead after fill3)
// h @10002112 overlays bin | o1 @11602112 overlays bin

__global__ __launch_bounds__(256) void k_bincount(const int* __restrict__ dst,
                                                  int* __restrict__ bktcnt,
                                                  int E, int nblk) {
    __shared__ int cnt[NRANGE];
    if (threadIdx.x < NRANGE) cnt[threadIdx.x] = 0;
    __syncthreads();
    int b0 = blockIdx.x * EB;
#pragma unroll
    for (int j = 0; j < 4; ++j) {
        int e = b0 + j * 256 + threadIdx.x;
        if (e < E) atomicAdd(&cnt[dst[e] / RS], 1);
    }
    __syncthreads();
    if (threadIdx.x < NRANGE)
        bktcnt[threadIdx.x * nblk + blockIdx.x] = cnt[threadIdx.x];
}

// exclusive scan (verified rounds 6-13); safe with out==in
__global__ __launch_bounds__(256) void k_scan_block(const int* __restrict__ in,
                                                    int* __restrict__ outp,
                                                    int* __restrict__ bsum, int n) {
    __shared__ int sh[256];
    int t = threadIdx.x, g = blockIdx.x * 256 + t;
    int v = (g < n) ? in[g] : 0;
    sh[t] = v; __syncthreads();
    for (int off = 1; off < 256; off <<= 1) {
        int a = (t >= off) ? sh[t - off] : 0;
        __syncthreads();
        sh[t] += a;
        __syncthreads();
    }
    if (g < n) outp[g] = sh[t] - v;
    if (t == 255) bsum[blockIdx.x] = sh[255];
}

// fused: per-node degree (sum of per-slice partials) + block scan
__global__ __launch_bounds__(256) void k_sumscan(const int* __restrict__ partials,
                                                 int* __restrict__ rowptr,
                                                 int* __restrict__ bsum, int n) {
    __shared__ int sh[256];
    int t = threadIdx.x, g = blockIdx.x * 256 + t;
    int v = 0;
    if (g < n) {
        int r = g / RS, b = g - r * RS;
        const int* p = partials + (size_t)(r * NS2) * RS + b;
#pragma unroll
        for (int s = 0; s < NS2; ++s) v += p[s * RS];
    }
    sh[t] = v; __syncthreads();
    for (int off = 1; off < 256; off <<= 1) {
        int a = (t >= off) ? sh[t - off] : 0;
        __syncthreads();
        sh[t] += a;
        __syncthreads();
    }
    if (g < n) rowptr[g] = sh[t] - v;
    if (t == 255) bsum[blockIdx.x] = sh[255];
}

__global__ __launch_bounds__(512) void k_scan_tops(int* __restrict__ bsum,
                                                   int* __restrict__ outp,
                                                   int nb, int n) {
    __shared__ int sh[512];
    int t = threadIdx.x;
    int v = (t < nb) ? bsum[t] : 0;
    sh[t] = v; __syncthreads();
    for (int off = 1; off < 512; off <<= 1) {
        int a = (t >= off) ? sh[t - off] : 0;
        __syncthreads();
        sh[t] += a;
        __syncthreads();
    }
    if (t < nb) bsum[t] = sh[t] - v;
    if (t == 511) outp[n] = sh[511];
}

__global__ __launch_bounds__(256) void k_scan_add(int* __restrict__ outp,
                                                  const int* __restrict__ bsum, int n) {
    int i = blockIdx.x * 256 + threadIdx.x;
    if (i < n) outp[i] += bsum[i >> 8];
}

// write each edge once into its bucket: ONE int2 scatter per edge
__global__ __launch_bounds__(256) void k_binfill(const int* __restrict__ src,
                                                 const int* __restrict__ dst,
                                                 const float* __restrict__ ew,
                                                 const int* __restrict__ bktcnt,
                                                 int2* __restrict__ bin,
                                                 int E, int nblk) {
    __shared__ int base[NRANGE];
    if (threadIdx.x < NRANGE)
        base[threadIdx.x] = bktcnt[threadIdx.x * nblk + blockIdx.x];
    __syncthreads();
    int b0 = blockIdx.x * EB;
#pragma unroll
    for (int j = 0; j < 4; ++j) {
        int e = b0 + j * 256 + threadIdx.x;
        if (e < E) {
            int d = dst[e];
            int r = d / RS;
            int pos = atomicAdd(&base[r], 1);          // LDS only
            bin[pos] = make_int2((src[e] << 12) | (d - r * RS),
                                 __float_as_int(ew[e]));
        }
    }
}

// per-(range, slice) LDS histogram; reads only its bucket slice
__global__ __launch_bounds__(256) void k_hist2(const int2* __restrict__ bin,
                                               const int* __restrict__ bktcnt,
                                               int* __restrict__ partials,
                                               int E, int nblk) {
    __shared__ int hist[RS];
    int r = blockIdx.x >> 5, s = blockIdx.x & (NS2 - 1);
    for (int t = threadIdx.x; t < RS; t += 256) hist[t] = 0;
    __syncthreads();
    int b0 = bktcnt[r * nblk];
    int b1 = (r == NRANGE - 1) ? E : bktcnt[(r + 1) * nblk];
    int len = b1 - b0, ss = (len + NS2 - 1) / NS2;
    int cs = b0 + s * ss, ce = min(cs + ss, b1);
    for (int j = cs + threadIdx.x; j < ce; j += 256)
        atomicAdd(&hist[bin[j].x & 4095], 1);
    __syncthreads();
    int* pp = partials + (size_t)(r * NS2 + s) * RS;
    for (int t = threadIdx.x; t < RS; t += 256) pp[t] = hist[t];
}

// per-slice counts -> exact slot starts
__global__ __launch_bounds__(256) void k_slicecur(int* __restrict__ partials,
                                                  const int* __restrict__ rowptr, int n) {
    int d = blockIdx.x * 256 + threadIdx.x;
    if (d >= n) return;
    int r = d / RS, b = d - r * RS;
    int* p = partials + (size_t)(r * NS2) * RS + b;
    int run = rowptr[d];
#pragma unroll
    for (int s = 0; s < NS2; ++s) {
        int c = p[s * RS];
        p[s * RS] = run;
        run += c;
    }
}

// place edges at exact csr positions; reads only its bucket slice
__global__ __launch_bounds__(256) void k_fill3(const int2* __restrict__ bin,
                                               const int* __restrict__ bktcnt,
                                               const int* __restrict__ partials,
                                               int2* __restrict__ csr,
                                               int E, int nblk) {
    __shared__ int cur[RS];
    int r = blockIdx.x >> 5, s = blockIdx.x & (NS2 - 1);
    const int* cp = partials + (size_t)(r * NS2 + s) * RS;
    for (int t = threadIdx.x; t < RS; t += 256) cur[t] = cp[t];
    __syncthreads();
    int b0 = bktcnt[r * nblk];
    int b1 = (r == NRANGE - 1) ? E : bktcnt[(r + 1) * nblk];
    int len = b1 - b0, ss = (len + NS2 - 1) / NS2;
    int cs = b0 + s * ss, ce = min(cs + ss, b1);
    for (int j = cs + threadIdx.x; j < ce; j += 256) {
        int2 p2 = bin[j];
        int pos = atomicAdd(&cur[p2.x & 4095], 1);    // LDS only
        csr[pos] = make_int2(p2.x >> 12, p2.y);
    }
}

// dinv[d] = rsqrt(1 + sum ew over csr row d)
__global__ __launch_bounds__(256) void k_wdeg(const int2* __restrict__ csr,
                                              const int* __restrict__ rowptr,
                                              float* __restrict__ dinv, int n) {
    int tid = blockIdx.x * 256 + threadIdx.x;
    int d = tid >> 4, f = tid & 15;
    if (d >= n) return;
    int e0 = rowptr[d], e1 = rowptr[d + 1];
    float w = 0.0f;
    for (int j = e0 + f; j < e1; j += 16) w += __int_as_float(csr[j].y);
#pragma unroll
    for (int o = 8; o; o >>= 1) w += __shfl_xor(w, o, 16);
    if (f == 0) dinv[d] = rsqrtf(1.0f + w);
}

// h = x @ W1. 4x4 register blocking: 8 ds_read_b128 per 64 FMA.
// x tile 256 rows x 32 k, column-rotated by (row>>2)&7: 16B-aligned float4
// AND stride-4-row reads are 2-way-max on banks (free). W1 [k4][f][kk]
// broadcast reads. LDS 64KB -> 2 blocks/CU.
__global__ __launch_bounds__(256) void k_gemm1(const float* __restrict__ x,
                                               const float* __restrict__ w1,
                                               float* __restrict__ h, int n) {
    __shared__ float wt[NF * NH];          // 32KB
    __shared__ float xs[GROWS * GK];       // 32KB
    for (int t = threadIdx.x; t < NF * NH; t += 256) {
        int k = t >> 4, f = t & 15;
        wt[(k >> 2) * 64 + (f << 2) + (k & 3)] = w1[t];
    }
    int rq = threadIdx.x >> 2;             // 0..63
    int fq = threadIdx.x & 3;              // 0..3
    int base = blockIdx.x * GROWS;
    float acc[4][4] = {{0.f}};
    for (int kc = 0; kc < NF / GK; ++kc) {
        __syncthreads();                   // xs safe to overwrite (also covers wt)
#pragma unroll
        for (int li = 0; li < 8; ++li) {
            int idx = li * 256 + threadIdx.x;     // 2048 float4 slots
            int row = idx >> 3, c4 = idx & 7;
            int rg = base + row; if (rg > n - 1) rg = n - 1;   // clamp (no OOB)
            float4 v = *(const float4*)(x + (size_t)rg * NF + kc * GK + c4 * 4);
            int slot = (c4 + (row >> 2)) & 7;     // rotate: bank-spread reads
            float* p = &xs[row * GK + slot * 4];
            p[0] = v.x; p[1] = v.y; p[2] = v.z; p[3] = v.w;
        }
        __syncthreads();
#pragma unroll
        for (int k4c = 0; k4c < GK / 4; ++k4c) {
            int k4 = kc * (GK / 4) + k4c;
            float4 wf[4];
#pragma unroll
            for (int c = 0; c < 4; ++c)
                wf[c] = *(const float4*)&wt[k4 * 64 + (fq * 4 + c) * 4];
#pragma unroll
            for (int i = 0; i < 4; ++i) {
                int row = rq * 4 + i;
                int slot = (k4c + rq) & 7;        // same rotation as store
                float4 xv = *(const float4*)&xs[row * GK + slot * 4];
#pragma unroll
                for (int c = 0; c < 4; ++c) {
                    acc[i][c] = fmaf(xv.x, wf[c].x, acc[i][c]);
                    acc[i][c] = fmaf(xv.y, wf[c].y, acc[i][c]);
                    acc[i][c] = fmaf(xv.z, wf[c].z, acc[i][c]);
                    acc[i][c] = fmaf(xv.w, wf[c].w, acc[i][c]);
                }
            }
        }
    }
#pragma unroll
    for (int i = 0; i < 4; ++i) {
        int r = base + rq * 4 + i;
        if (r < n) {
            float4 o = make_float4(acc[i][0], acc[i][1], acc[i][2], acc[i][3]);
            *(float4*)(h + (size_t)r * NH + fq * 4) = o;
        }
    }
}

// layer-1 gather with fused bias+relu: out = relu(agg + b1[f])
__global__ __launch_bounds__(256) void k_gather_relu(const float* __restrict__ in,
                                                     const float* __restrict__ dinv,
                                                     const int* __restrict__ rowptr,
                                                     const int2* __restrict__ csr,
                                                     const float* __restrict__ b1,
                                                     float* __restrict__ out, int n) {
    int tid = blockIdx.x * 256 + threadIdx.x;
    int d = tid >> 4, f = tid & 15;
    if (d >= n) return;
    float di = dinv[d];
    float acc = in[tid] * di * di;
    int e0 = rowptr[d], e1 = rowptr[d + 1];
    for (int j = e0; j < e1; ++j) {
        int2 ent = csr[j];
        float nrm = dinv[ent.x] * __int_as_float(ent.y) * di;
        acc = fmaf(in[ent.x * NH + f], nrm, acc);
    }
    out[tid] = fmaxf(acc + b1[f], 0.0f);
}

// layer-2 gather (plain)
__global__ __launch_bounds__(256) void k_gather(const float* __restrict__ in,
                                                const float* __restrict__ dinv,
                                                const int* __restrict__ rowptr,
                                                const int2* __restrict__ csr,
                                                float* __restrict__ out, int n) {
    int tid = blockIdx.x * 256 + threadIdx.x;
    int d = tid >> 4, f = tid & 15;
    if (d >= n) return;
    float di = dinv[d];
    float acc = in[tid] * di * di;
    int e0 = rowptr[d], e1 = rowptr[d + 1];
    for (int j = e0; j < e1; ++j) {
        int2 ent = csr[j];
        float nrm = dinv[ent.x] * __int_as_float(ent.y) * di;
        acc = fmaf(in[ent.x * NH + f], nrm, acc);
    }
    out[tid] = acc;
}

__global__ __launch_bounds__(256) void k_out(const float* __restrict__ agg,
                                             const float* __restrict__ w2,
                                             const float* __restrict__ b2,
                                             float* __restrict__ out, int n) {
    __shared__ float w2s[NH * 40];
    __shared__ float b2s[40];
    for (int t = threadIdx.x; t < NH * 40; t += 256) w2s[t] = w2[t];
    if (threadIdx.x < 40) b2s[threadIdx.x] = b2[threadIdx.x];
    __syncthreads();
    int i = blockIdx.x * 256 + threadIdx.x;
    if (i >= n) return;
    float v[NH];
    const float4* ap = (const float4*)(agg + (size_t)i * NH);
#pragma unroll
    for (int m = 0; m < 4; ++m) {
        float4 t4 = ap[m];
        v[4 * m] = t4.x; v[4 * m + 1] = t4.y; v[4 * m + 2] = t4.z; v[4 * m + 3] = t4.w;
    }
    float z[40];
#pragma unroll
    for (int c = 0; c < 40; ++c) {
        float a = b2s[c];
#pragma unroll
        for (int ff = 0; ff < NH; ++ff) a = fmaf(v[ff], w2s[ff * 40 + c], a);
        z[c] = a;
    }
    float mx = z[0];
#pragma unroll
    for (int c = 1; c < 40; ++c) mx = fmaxf(mx, z[c]);
    float sum = 0.0f;
#pragma unroll
    for (int c = 0; c < 40; ++c) sum += expf(z[c] - mx);
    float ls = mx + logf(sum);
    float4* op = (float4*)(out + (size_t)i * 40);
#pragma unroll
    for (int m = 0; m < 10; ++m) {
        float4 o;
        o.x = z[4 * m] - ls; o.y = z[4 * m + 1] - ls;
        o.z = z[4 * m + 2] - ls; o.w = z[4 * m + 3] - ls;
        op[m] = o;
    }
}

extern "C" void kernel_launch(void* const* d_in, const int* in_sizes, int n_in,
                              void* d_out, int out_size, void* d_ws, size_t ws_size,
                              hipStream_t stream) {
    const float* x  = (const float*)d_in[0];
    const int*   ei = (const int*)d_in[1];
    const float* ew = (const float*)d_in[2];
    const float* w1 = (const float*)d_in[3];
    const float* b1 = (const float*)d_in[4];
    const float* w2 = (const float*)d_in[5];
    const float* b2 = (const float*)d_in[6];
    float* out = (float*)d_out;

    int n = in_sizes[0] / NF;      // 100000 (= NRANGE*RS)
    int E = in_sizes[2];           // 3200000
    const int* src = ei;
    const int* dst = ei + E;

    float* ws       = (float*)d_ws;
    float* dinv     = ws;                       // n
    int*   bsum     = (int*)(ws + 200000);      // 1024
    int*   rowptr   = (int*)(ws + 201024);      // n+1
    int*   bsum2    = (int*)(ws + 301056);      // 1024
    int*   bktcnt   = (int*)(ws + 302080);      // 100032, scanned in place
    int*   partials = (int*)(ws + 402112);      // NRANGE*NS2*RS = 3.2M
    int2*  csr      = (int2*)(ws + 3602112);    // 2*E ints
    int2*  bin      = (int2*)(ws + 10002112);   // 2*E ints, dead after fill3
    float* h        = ws + 10002112;            // overlays bin
    float* o1       = ws + 11602112;            // overlays bin

    int nblk  = (E + EB - 1) / EB;              // 3125 bin blocks
    int ncnt  = NRANGE * nblk;                  // 100000 counts
    int nb_c  = (ncnt + 255) / 256;             // 391
    int nb_n  = (n + 255) / 256;                // 391
    int nb_nf = (n * NH + 255) / 256;           // 6250
    int nb_g  = (n + GROWS - 1) / GROWS;        // 391 gemm blocks

    // 1) bin counts + exact bases (scan in place)
    k_bincount<<<nblk, 256, 0, stream>>>(dst, bktcnt, E, nblk);
    k_scan_block<<<nb_c, 256, 0, stream>>>(bktcnt, bktcnt, bsum2, ncnt);
    k_scan_tops<<<1, 512, 0, stream>>>(bsum2, bktcnt, nb_c, ncnt);
    k_scan_add<<<nb_c, 256, 0, stream>>>(bktcnt, bsum2, ncnt);
    // 2) bin edges (each edge written once, single int2 scatter)
    k_binfill<<<nblk, 256, 0, stream>>>(src, dst, ew, bktcnt, bin, E, nblk);
    // 3) per-range hist -> rowptr -> exact CSR
    k_hist2<<<NRANGE * NS2, 256, 0, stream>>>(bin, bktcnt, partials, E, nblk);
    k_sumscan<<<nb_n, 256, 0, stream>>>(partials, rowptr, bsum, n);
    k_scan_tops<<<1, 512, 0, stream>>>(bsum, rowptr, nb_n, n);
    k_scan_add<<<nb_n, 256, 0, stream>>>(rowptr, bsum, n);
    k_slicecur<<<nb_n, 256, 0, stream>>>(partials, rowptr, n);
    k_fill3<<<NRANGE * NS2, 256, 0, stream>>>(bin, bktcnt, partials, csr, E, nblk);
    // 4) GCN pipeline
    k_wdeg<<<nb_nf, 256, 0, stream>>>(csr, rowptr, dinv, n);
    k_gemm1<<<nb_g, 256, 0, stream>>>(x, w1, h, n);
    k_gather_relu<<<nb_nf, 256, 0, stream>>>(h, dinv, rowptr, csr, b1, o1, n);
    k_gather<<<nb_nf, 256, 0, stream>>>(o1, dinv, rowptr, csr, h, n);
    k_out<<<nb_n, 256, 0, stream>>>(h, w2, b2, out, n);
}

// Round 15
// 373.247 us; speedup vs baseline: 1.1232x; 1.1232x over previous
//
#include <hip/hip_runtime.h>

// GCN 2-layer. Round-14 post-mortem: gemm1 125us with VALU 13% / HBM 11% /
// occ 17% -- duty-cycle bound: barrier -> burst loads -> drain -> compute
// serializes memory and ALU phases. Fix: double-buffered x tile (GK=16,
// 2x16KB + 32KB wt = 64KB, 2 blocks/CU): loads for chunk k+1 issue into
// regs BEFORE compute of chunk k; vmcnt drain hides behind compute.

#define NF 512
#define NH 16
#define NRANGE 32
#define NS2 32
#define RS 3125           // nodes per range = 100000/32
#define EB 1024           // edges per bin block
#define GROWS 256         // gemm rows per block
#define GK 16             // gemm k-chunk (double-buffered)

__global__ __launch_bounds__(256) void k_bincount(const int* __restrict__ dst,
                                                  int* __restrict__ bktcnt,
                                                  int E, int nblk) {
    __shared__ int cnt[NRANGE];
    if (threadIdx.x < NRANGE) cnt[threadIdx.x] = 0;
    __syncthreads();
    int b0 = blockIdx.x * EB;
#pragma unroll
    for (int j = 0; j < 4; ++j) {
        int e = b0 + j * 256 + threadIdx.x;
        if (e < E) atomicAdd(&cnt[dst[e] / RS], 1);
    }
    __syncthreads();
    if (threadIdx.x < NRANGE)
        bktcnt[threadIdx.x * nblk + blockIdx.x] = cnt[threadIdx.x];
}

// exclusive scan (verified rounds 6-14); safe with out==in
__global__ __launch_bounds__(256) void k_scan_block(const int* __restrict__ in,
                                                    int* __restrict__ outp,
                                                    int* __restrict__ bsum, int n) {
    __shared__ int sh[256];
    int t = threadIdx.x, g = blockIdx.x * 256 + t;
    int v = (g < n) ? in[g] : 0;
    sh[t] = v; __syncthreads();
    for (int off = 1; off < 256; off <<= 1) {
        int a = (t >= off) ? sh[t - off] : 0;
        __syncthreads();
        sh[t] += a;
        __syncthreads();
    }
    if (g < n) outp[g] = sh[t] - v;
    if (t == 255) bsum[blockIdx.x] = sh[255];
}

// fused: per-node degree (sum of per-slice partials) + block scan
__global__ __launch_bounds__(256) void k_sumscan(const int* __restrict__ partials,
                                                 int* __restrict__ rowptr,
                                                 int* __restrict__ bsum, int n) {
    __shared__ int sh[256];
    int t = threadIdx.x, g = blockIdx.x * 256 + t;
    int v = 0;
    if (g < n) {
        int r = g / RS, b = g - r * RS;
        const int* p = partials + (size_t)(r * NS2) * RS + b;
#pragma unroll
        for (int s = 0; s < NS2; ++s) v += p[s * RS];
    }
    sh[t] = v; __syncthreads();
    for (int off = 1; off < 256; off <<= 1) {
        int a = (t >= off) ? sh[t - off] : 0;
        __syncthreads();
        sh[t] += a;
        __syncthreads();
    }
    if (g < n) rowptr[g] = sh[t] - v;
    if (t == 255) bsum[blockIdx.x] = sh[255];
}

__global__ __launch_bounds__(512) void k_scan_tops(int* __restrict__ bsum,
                                                   int* __restrict__ outp,
                                                   int nb, int n) {
    __shared__ int sh[512];
    int t = threadIdx.x;
    int v = (t < nb) ? bsum[t] : 0;
    sh[t] = v; __syncthreads();
    for (int off = 1; off < 512; off <<= 1) {
        int a = (t >= off) ? sh[t - off] : 0;
        __syncthreads();
        sh[t] += a;
        __syncthreads();
    }
    if (t < nb) bsum[t] = sh[t] - v;
    if (t == 511) outp[n] = sh[511];
}

__global__ __launch_bounds__(256) void k_scan_add(int* __restrict__ outp,
                                                  const int* __restrict__ bsum, int n) {
    int i = blockIdx.x * 256 + threadIdx.x;
    if (i < n) outp[i] += bsum[i >> 8];
}

// write each edge once into its bucket: ONE int2 scatter per edge
__global__ __launch_bounds__(256) void k_binfill(const int* __restrict__ src,
                                                 const int* __restrict__ dst,
                                                 const float* __restrict__ ew,
                                                 const int* __restrict__ bktcnt,
                                                 int2* __restrict__ bin,
                                                 int E, int nblk) {
    __shared__ int base[NRANGE];
    if (threadIdx.x < NRANGE)
        base[threadIdx.x] = bktcnt[threadIdx.x * nblk + blockIdx.x];
    __syncthreads();
    int b0 = blockIdx.x * EB;
#pragma unroll
    for (int j = 0; j < 4; ++j) {
        int e = b0 + j * 256 + threadIdx.x;
        if (e < E) {
            int d = dst[e];
            int r = d / RS;
            int pos = atomicAdd(&base[r], 1);          // LDS only
            bin[pos] = make_int2((src[e] << 12) | (d - r * RS),
                                 __float_as_int(ew[e]));
        }
    }
}

// per-(range, slice) LDS histogram; reads only its bucket slice
__global__ __launch_bounds__(256) void k_hist2(const int2* __restrict__ bin,
                                               const int* __restrict__ bktcnt,
                                               int* __restrict__ partials,
                                               int E, int nblk) {
    __shared__ int hist[RS];
    int r = blockIdx.x >> 5, s = blockIdx.x & (NS2 - 1);
    for (int t = threadIdx.x; t < RS; t += 256) hist[t] = 0;
    __syncthreads();
    int b0 = bktcnt[r * nblk];
    int b1 = (r == NRANGE - 1) ? E : bktcnt[(r + 1) * nblk];
    int len = b1 - b0, ss = (len + NS2 - 1) / NS2;
    int cs = b0 + s * ss, ce = min(cs + ss, b1);
    for (int j = cs + threadIdx.x; j < ce; j += 256)
        atomicAdd(&hist[bin[j].x & 4095], 1);
    __syncthreads();
    int* pp = partials + (size_t)(r * NS2 + s) * RS;
    for (int t = threadIdx.x; t < RS; t += 256) pp[t] = hist[t];
}

// per-slice counts -> exact slot starts
__global__ __launch_bounds__(256) void k_slicecur(int* __restrict__ partials,
                                                  const int* __restrict__ rowptr, int n) {
    int d = blockIdx.x * 256 + threadIdx.x;
    if (d >= n) return;
    int r = d / RS, b = d - r * RS;
    int* p = partials + (size_t)(r * NS2) * RS + b;
    int run = rowptr[d];
#pragma unroll
    for (int s = 0; s < NS2; ++s) {
        int c = p[s * RS];
        p[s * RS] = run;
        run += c;
    }
}

// place edges at exact csr positions; reads only its bucket slice
__global__ __launch_bounds__(256) void k_fill3(const int2* __restrict__ bin,
                                               const int* __restrict__ bktcnt,
                                               const int* __restrict__ partials,
                                               int2* __restrict__ csr,
                                               int E, int nblk) {
    __shared__ int cur[RS];
    int r = blockIdx.x >> 5, s = blockIdx.x & (NS2 - 1);
    const int* cp = partials + (size_t)(r * NS2 + s) * RS;
    for (int t = threadIdx.x; t < RS; t += 256) cur[t] = cp[t];
    __syncthreads();
    int b0 = bktcnt[r * nblk];
    int b1 = (r == NRANGE - 1) ? E : bktcnt[(r + 1) * nblk];
    int len = b1 - b0, ss = (len + NS2 - 1) / NS2;
    int cs = b0 + s * ss, ce = min(cs + ss, b1);
    for (int j = cs + threadIdx.x; j < ce; j += 256) {
        int2 p2 = bin[j];
        int pos = atomicAdd(&cur[p2.x & 4095], 1);    // LDS only
        csr[pos] = make_int2(p2.x >> 12, p2.y);
    }
}

// dinv[d] = rsqrt(1 + sum ew over csr row d)
__global__ __launch_bounds__(256) void k_wdeg(const int2* __restrict__ csr,
                                              const int* __restrict__ rowptr,
                                              float* __restrict__ dinv, int n) {
    int tid = blockIdx.x * 256 + threadIdx.x;
    int d = tid >> 4, f = tid & 15;
    if (d >= n) return;
    int e0 = rowptr[d], e1 = rowptr[d + 1];
    float w = 0.0f;
    for (int j = e0 + f; j < e1; j += 16) w += __int_as_float(csr[j].y);
#pragma unroll
    for (int o = 8; o; o >>= 1) w += __shfl_xor(w, o, 16);
    if (f == 0) dinv[d] = rsqrtf(1.0f + w);
}

// h = x @ W1, double-buffered. Per chunk: issue next chunk's 4 float4 loads
// into regs, THEN compute current chunk from LDS, then drain+ds_write.
__global__ __launch_bounds__(256) void k_gemm1(const float* __restrict__ x,
                                               const float* __restrict__ w1,
                                               float* __restrict__ h, int n) {
    __shared__ float wt[NF * NH];          // 32KB, read-only after init
    __shared__ float xs[2][GROWS * GK];    // 2 x 16KB
    for (int t = threadIdx.x; t < NF * NH; t += 256) {
        int k = t >> 4, f = t & 15;
        wt[(k >> 2) * 64 + (f << 2) + (k & 3)] = w1[t];
    }
    int rq = threadIdx.x >> 2;             // 0..63 (row quad)
    int fq = threadIdx.x & 3;              // 0..3  (col quad)
    int base = blockIdx.x * GROWS;
    float4 stage[4];
#define LOAD_CHUNK(kc)                                                        \
    _Pragma("unroll")                                                         \
    for (int li = 0; li < 4; ++li) {                                          \
        int idx = li * 256 + threadIdx.x;                                     \
        int row = idx >> 2, c4 = idx & 3;                                     \
        int rg = base + row; if (rg > n - 1) rg = n - 1;                      \
        stage[li] = *(const float4*)(x + (size_t)rg * NF + (kc) * GK + c4 * 4);\
    }
#define WRITE_CHUNK(b)                                                        \
    _Pragma("unroll")                                                         \
    for (int li = 0; li < 4; ++li) {                                          \
        int idx = li * 256 + threadIdx.x;                                     \
        int row = idx >> 2, c4 = idx & 3;                                     \
        int slot = (c4 + (row >> 2)) & 3;                                     \
        float* p = &xs[b][row * GK + slot * 4];                               \
        p[0] = stage[li].x; p[1] = stage[li].y;                               \
        p[2] = stage[li].z; p[3] = stage[li].w;                               \
    }
    float acc[4][4] = {{0.f}};
    LOAD_CHUNK(0)
    WRITE_CHUNK(0)
    __syncthreads();                       // also covers wt
    for (int kc = 0; kc < NF / GK; ++kc) {
        if (kc + 1 < NF / GK) { LOAD_CHUNK(kc + 1) }   // in flight over compute
        int b = kc & 1;
#pragma unroll
        for (int k4c = 0; k4c < GK / 4; ++k4c) {
            int k4 = kc * (GK / 4) + k4c;
            float4 wf[4];
#pragma unroll
            for (int c = 0; c < 4; ++c)
                wf[c] = *(const float4*)&wt[k4 * 64 + (fq * 4 + c) * 4];
#pragma unroll
            for (int i = 0; i < 4; ++i) {
                int row = rq * 4 + i;
                int slot = (k4c + rq) & 3;
                float4 xv = *(const float4*)&xs[b][row * GK + slot * 4];
#pragma unroll
                for (int c = 0; c < 4; ++c) {
                    acc[i][c] = fmaf(xv.x, wf[c].x, acc[i][c]);
                    acc[i][c] = fmaf(xv.y, wf[c].y, acc[i][c]);
                    acc[i][c] = fmaf(xv.z, wf[c].z, acc[i][c]);
                    acc[i][c] = fmaf(xv.w, wf[c].w, acc[i][c]);
                }
            }
        }
        if (kc + 1 < NF / GK) {
            __syncthreads();               // all lanes done with buf b^1 reads
            WRITE_CHUNK((kc + 1) & 1)      // drains vmcnt here, behind compute
            __syncthreads();               // writes visible for next chunk
        }
    }
#pragma unroll
    for (int i = 0; i < 4; ++i) {
        int r = base + rq * 4 + i;
        if (r < n) {
            float4 o = make_float4(acc[i][0], acc[i][1], acc[i][2], acc[i][3]);
            *(float4*)(h + (size_t)r * NH + fq * 4) = o;
        }
    }
#undef LOAD_CHUNK
#undef WRITE_CHUNK
}

// layer-1 gather with fused bias+relu: out = relu(agg + b1[f])
__global__ __launch_bounds__(256) void k_gather_relu(const float* __restrict__ in,
                                                     const float* __restrict__ dinv,
                                                     const int* __restrict__ rowptr,
                                                     const int2* __restrict__ csr,
                                                     const float* __restrict__ b1,
                                                     float* __restrict__ out, int n) {
    int tid = blockIdx.x * 256 + threadIdx.x;
    int d = tid >> 4, f = tid & 15;
    if (d >= n) return;
    float di = dinv[d];
    float acc = in[tid] * di * di;
    int e0 = rowptr[d], e1 = rowptr[d + 1];
    for (int j = e0; j < e1; ++j) {
        int2 ent = csr[j];
        float nrm = dinv[ent.x] * __int_as_float(ent.y) * di;
        acc = fmaf(in[ent.x * NH + f], nrm, acc);
    }
    out[tid] = fmaxf(acc + b1[f], 0.0f);
}

// layer-2 gather (plain)
__global__ __launch_bounds__(256) void k_gather(const float* __restrict__ in,
                                                const float* __restrict__ dinv,
                                                const int* __restrict__ rowptr,
                                                const int2* __restrict__ csr,
                                                float* __restrict__ out, int n) {
    int tid = blockIdx.x * 256 + threadIdx.x;
    int d = tid >> 4, f = tid & 15;
    if (d >= n) return;
    float di = dinv[d];
    float acc = in[tid] * di * di;
    int e0 = rowptr[d], e1 = rowptr[d + 1];
    for (int j = e0; j < e1; ++j) {
        int2 ent = csr[j];
        float nrm = dinv[ent.x] * __int_as_float(ent.y) * di;
        acc = fmaf(in[ent.x * NH + f], nrm, acc);
    }
    out[tid] = acc;
}

__global__ __launch_bounds__(256) void k_out(const float* __restrict__ agg,
                                             const float* __restrict__ w2,
                                             const float* __restrict__ b2,
                                             float* __restrict__ out, int n) {
    __shared__ float w2s[NH * 40];
    __shared__ float b2s[40];
    for (int t = threadIdx.x; t < NH * 40; t += 256) w2s[t] = w2[t];
    if (threadIdx.x < 40) b2s[threadIdx.x] = b2[threadIdx.x];
    __syncthreads();
    int i = blockIdx.x * 256 + threadIdx.x;
    if (i >= n) return;
    float v[NH];
    const float4* ap = (const float4*)(agg + (size_t)i * NH);
#pragma unroll
    for (int m = 0; m < 4; ++m) {
        float4 t4 = ap[m];
        v[4 * m] = t4.x; v[4 * m + 1] = t4.y; v[4 * m + 2] = t4.z; v[4 * m + 3] = t4.w;
    }
    float z[40];
#pragma unroll
    for (int c = 0; c < 40; ++c) {
        float a = b2s[c];
#pragma unroll
        for (int ff = 0; ff < NH; ++ff) a = fmaf(v[ff], w2s[ff * 40 + c], a);
        z[c] = a;
    }
    float mx = z[0];
#pragma unroll
    for (int c = 1; c < 40; ++c) mx = fmaxf(mx, z[c]);
    float sum = 0.0f;
#pragma unroll
    for (int c = 0; c < 40; ++c) sum += expf(z[c] - mx);
    float ls = mx + logf(sum);
    float4* op = (float4*)(out + (size_t)i * 40);
#pragma unroll
    for (int m = 0; m < 10; ++m) {
        float4 o;
        o.x = z[4 * m] - ls; o.y = z[4 * m + 1] - ls;
        o.z = z[4 * m + 2] - ls; o.w = z[4 * m + 3] - ls;
        op[m] = o;
    }
}

extern "C" void kernel_launch(void* const* d_in, const int* in_sizes, int n_in,
                              void* d_out, int out_size, void* d_ws, size_t ws_size,
                              hipStream_t stream) {
    const float* x  = (const float*)d_in[0];
    const int*   ei = (const int*)d_in[1];
    const float* ew = (const float*)d_in[2];
    const float* w1 = (const float*)d_in[3];
    const float* b1 = (const float*)d_in[4];
    const float* w2 = (const float*)d_in[5];
    const float* b2 = (const float*)d_in[6];
    float* out = (float*)d_out;

    int n = in_sizes[0] / NF;      // 100000 (= NRANGE*RS)
    int E = in_sizes[2];           // 3200000
    const int* src = ei;
    const int* dst = ei + E;

    float* ws       = (float*)d_ws;
    float* dinv     = ws;                       // n
    int*   bsum     = (int*)(ws + 200000);      // 1024
    int*   rowptr   = (int*)(ws + 201024);      // n+1
    int*   bsum2    = (int*)(ws + 301056);      // 1024
    int*   bktcnt   = (int*)(ws + 302080);      // 100032, scanned in place
    int*   partials = (int*)(ws + 402112);      // NRANGE*NS2*RS = 3.2M
    int2*  csr      = (int2*)(ws + 3602112);    // 2*E ints
    int2*  bin      = (int2*)(ws + 10002112);   // 2*E ints, dead after fill3
    float* h        = ws + 10002112;            // overlays bin
    float* o1       = ws + 11602112;            // overlays bin

    int nblk  = (E + EB - 1) / EB;              // 3125 bin blocks
    int ncnt  = NRANGE * nblk;                  // 100000 counts
    int nb_c  = (ncnt + 255) / 256;             // 391
    int nb_n  = (n + 255) / 256;                // 391
    int nb_nf = (n * NH + 255) / 256;           // 6250
    int nb_g  = (n + GROWS - 1) / GROWS;        // 391 gemm blocks

    // 1) bin counts + exact bases (scan in place)
    k_bincount<<<nblk, 256, 0, stream>>>(dst, bktcnt, E, nblk);
    k_scan_block<<<nb_c, 256, 0, stream>>>(bktcnt, bktcnt, bsum2, ncnt);
    k_scan_tops<<<1, 512, 0, stream>>>(bsum2, bktcnt, nb_c, ncnt);
    k_scan_add<<<nb_c, 256, 0, stream>>>(bktcnt, bsum2, ncnt);
    // 2) bin edges (each edge written once, single int2 scatter)
    k_binfill<<<nblk, 256, 0, stream>>>(src, dst, ew, bktcnt, bin, E, nblk);
    // 3) per-range hist -> rowptr -> exact CSR
    k_hist2<<<NRANGE * NS2, 256, 0, stream>>>(bin, bktcnt, partials, E, nblk);
    k_sumscan<<<nb_n, 256, 0, stream>>>(partials, rowptr, bsum, n);
    k_scan_tops<<<1, 512, 0, stream>>>(bsum, rowptr, nb_n, n);
    k_scan_add<<<nb_n, 256, 0, stream>>>(rowptr, bsum, n);
    k_slicecur<<<nb_n, 256, 0, stream>>>(partials, rowptr, n);
    k_fill3<<<NRANGE * NS2, 256, 0, stream>>>(bin, bktcnt, partials, csr, E, nblk);
    // 4) GCN pipeline
    k_wdeg<<<nb_nf, 256, 0, stream>>>(csr, rowptr, dinv, n);
    k_gemm1<<<nb_g, 256, 0, stream>>>(x, w1, h, n);
    k_gather_relu<<<nb_nf, 256, 0, stream>>>(h, dinv, rowptr, csr, b1, o1, n);
    k_gather<<<nb_nf, 256, 0, stream>>>(o1, dinv, rowptr, csr, h, n);
    k_out<<<nb_n, 256, 0, stream>>>(h, w2, b2, out, n);
}